// Round 14
// baseline (354.228 us; speedup 1.0000x reference)
//
#include <hip/hip_runtime.h>
#include <cfloat>
#include <climits>
#include <math.h>

#define BN 16
#define QN 4096
#define GN 256
#define CN 80
#define NPART 64           // row parts in k_main (64 rows each)
#define RPP (QN / NPART)   // 64

typedef unsigned long long u64;

__device__ __forceinline__ bool lexLessF(float a, int ia, float b, int ib) {
    return (a < b) || (a == b && ia < ib);
}
// IEEE order-isomorphic u32 key (no NaNs in this data)
__device__ __forceinline__ unsigned int fkey(float f) {
    unsigned int b = __float_as_uint(f);
    return b ^ ((b >> 31) ? 0xFFFFFFFFu : 0x80000000u);
}
__device__ __forceinline__ float funkey(unsigned int k) {
    unsigned int b = k ^ ((k >> 31) ? 0x80000000u : 0xFFFFFFFFu);
    return __uint_as_float(b);
}

// ---------------- fully-fused front-end: prm | class | fg | cost | selection ----------------
__global__ __launch_bounds__(256) void k_main(
    const float* __restrict__ logits, const int* __restrict__ labels,
    const float* __restrict__ gtb, const float* __restrict__ gtt,
    const float* __restrict__ gtr, const float* __restrict__ imgt,
    const float* __restrict__ pboxes, const float* __restrict__ pposes,
    const float* __restrict__ img,
    float* __restrict__ costT, u64* __restrict__ rec) {
#pragma clang fp contract(off)
    const int j = threadIdx.x;
    const int b = blockIdx.x >> 6;
    const int part = blockIdx.x & 63;
    const int i0 = part * RPP;

    __shared__ float Lc[RPP * CN];       // 64x80 2x focal class costs (20.5 KB)
    __shared__ float Lb[8 * GN];         // X0,Y0,X1,Y1,LOX,HIX,LOY,HIY per column (8 KB)
    __shared__ u64 Lboth[RPP][4];        // both-bitmask per row (2 KB)
    __shared__ unsigned int Lany[RPP * 4];
    __shared__ float4 Rsh[RPP][5];

    // ---- 1. per-column params (identical expressions) ----
    const float* g = gtb + ((size_t)(b * GN + j)) * 4;
    const float g0 = g[0], g1 = g[1], g2 = g[2], g3 = g[3];
    const float* it = imgt + ((size_t)(b * GN + j)) * 4;
    const float gn0 = g0 / it[0], gn1 = g1 / it[1], gn2 = g2 / it[2], gn3 = g3 / it[3];
    const float t0 = gtt[(b * GN + j) * 3 + 0], t1 = gtt[(b * GN + j) * 3 + 1],
                t2 = gtt[(b * GN + j) * 3 + 2];
    const float r0 = gtr[(b * GN + j) * 3 + 0], r1 = gtr[(b * GN + j) * 3 + 1],
                r2 = gtr[(b * GN + j) * 3 + 2];
    const float ga = (g2 - g0) * (g3 - g1);
    {
        float gcx = (g0 + g2) * 0.5f, gcy = (g1 + g3) * 0.5f;
        float gw = g2 - g0, gh = g3 - g1;
        float X0 = gcx - gw * 0.5f, Y0 = gcy - gh * 0.5f;
        float X1 = gcx + gw * 0.5f, Y1 = gcy + gh * 0.5f;
        float Wd = X1 - X0, Hd = Y1 - Y0;
        Lb[0 * GN + j] = X0;  Lb[1 * GN + j] = Y0;
        Lb[2 * GN + j] = X1;  Lb[3 * GN + j] = Y1;
        Lb[4 * GN + j] = gcx - 2.5f * Wd; Lb[5 * GN + j] = gcx + 2.5f * Wd;
        Lb[6 * GN + j] = gcy - 2.5f * Hd; Lb[7 * GN + j] = gcy + 2.5f * Hd;
    }
    const int lab = labels[b * GN + j];

    // ---- 2. class focal for the block's 64 rows x 80 classes (contiguous 20 KB span) ----
    const float* lbase = logits + ((size_t)(b * QN + i0)) * CN;
#pragma unroll
    for (int q = 0; q < 20; q++) {
        int idx = q * 256 + j;
        float x = lbase[idx];
        float e = (float)exp(-(double)x);
        float pr = 1.0f / (1.0f + e);
        float om = 1.0f - pr;
        float lneg = (float)log((double)(om + 1e-8f));
        float lpos = (float)log((double)(pr + 1e-8f));
        float neg = (0.75f * (pr * pr)) * (-lneg);
        float pos = (0.25f * (om * om)) * (-lpos);
        Lc[idx] = 2.0f * (pos - neg);    // pre-doubled: 2*cc is exact in f32
    }

    // ---- 3. row staging ----
    if (threadIdx.x < RPP) {
        const int i = i0 + threadIdx.x;
        const float im0 = img[b * 4 + 0], im1 = img[b * 4 + 1];
        const float im2 = img[b * 4 + 2], im3 = img[b * 4 + 3];
        const float4 bx = *reinterpret_cast<const float4*>(pboxes + ((size_t)(b * QN + i)) * 4);
        const float b0 = bx.x, b1 = bx.y, b2 = bx.z, b3 = bx.w;
        const float2* pp2 = reinterpret_cast<const float2*>(pposes + ((size_t)(b * QN + i)) * 6);
        const float2 q0 = pp2[0], q1 = pp2[1], q2 = pp2[2];
        const float bn0 = b0 / im0, bn1 = b1 / im1, bn2 = b2 / im2, bn3 = b3 / im3;
        const float a1 = (b2 - b0) * (b3 - b1);
        const float ax = (b0 + b2) * 0.5f, ay = (b1 + b3) * 0.5f;
        Rsh[threadIdx.x][0] = make_float4(b0, b1, b2, b3);
        Rsh[threadIdx.x][1] = make_float4(bn0, bn1, bn2, bn3);
        Rsh[threadIdx.x][2] = make_float4(ax, ay, a1, 0.0f);
        Rsh[threadIdx.x][3] = make_float4(q0.x, q0.y, q1.x, q1.y);
        Rsh[threadIdx.x][4] = make_float4(q2.x, q2.y, 0.0f, 0.0f);
    }
    __syncthreads();

    // ---- 4. fg + both-bits: thread t -> row t&63, gt chunk t>>6 (64 gts) ----
    {
        const int r = threadIdx.x & 63, ch = threadIdx.x >> 6;
        const float axr = Rsh[r][2].x, ayr = Rsh[r][2].y;
        bool any = false;
        u64 bothbits = 0;
        const int jb = ch * 64;
#pragma unroll 8
        for (int m = 0; m < 64; m++) {
            int jj = jb + m;
            bool ib = (axr > Lb[0 * GN + jj]) && (axr < Lb[2 * GN + jj]) &&
                      (ayr > Lb[1 * GN + jj]) && (ayr < Lb[3 * GN + jj]);
            bool ic = (axr > Lb[4 * GN + jj]) && (axr < Lb[5 * GN + jj]) &&
                      (ayr > Lb[6 * GN + jj]) && (ayr < Lb[7 * GN + jj]);
            any |= (ib || ic);
            if (ib && ic) bothbits |= (1ull << m);
        }
        Lany[r * 4 + ch] = any ? 1u : 0u;
        Lboth[r][ch] = bothbits;
    }
    __syncthreads();
    if (threadIdx.x < RPP) {
        unsigned int a = 0;
#pragma unroll
        for (int c = 0; c < 4; c++) a |= Lany[threadIdx.x * 4 + c];
        Rsh[threadIdx.x][2].w = a ? 0.0f : 10000.0f;   // fgadd folded into row record
    }
    __syncthreads();

    // ---- 5. cost + selection main loop ----
    float* CT = costT + ((size_t)(b * QN) + i0) * GN + j;
    const int jw = j >> 6, jb63 = j & 63;

    u64 ck[5]; float iv[5];
#pragma unroll
    for (int k = 0; k < 5; k++) { ck[k] = ~0ull; iv[k] = -1.0f; }

    for (int r = 0; r < RPP; r++) {
        const int i = i0 + r;
        const float4 R0 = Rsh[r][0];
        const float4 R1 = Rsh[r][1];
        const float4 R2 = Rsh[r][2];
        const float4 R3 = Rsh[r][3];
        const float4 R4 = Rsh[r][4];
        const float b0 = R0.x, b1 = R0.y, b2 = R0.z, b3 = R0.w;
        const float bn0 = R1.x, bn1 = R1.y, bn2 = R1.z, bn3 = R1.w;
        const float a1 = R2.z, fgadd = R2.w;
        const float p0 = R3.x, p1 = R3.y, p2 = R3.z, p3 = R3.w;
        const float p4 = R4.x, p5 = R4.y;
        const float cc2 = Lc[r * CN + lab];
        const bool both = (Lboth[r][jw] >> jb63) & 1;

        // iou / giou (f32, reference op order)
        float ltx = fmaxf(b0, g0), lty = fmaxf(b1, g1);
        float rbx = fminf(b2, g2), rby = fminf(b3, g3);
        float w = fmaxf(rbx - ltx, 0.0f), h = fmaxf(rby - lty, 0.0f);
        float inter = w * h;
        float uni = (a1 + ga) - inter;
        float iou = inter / uni;
        float eltx = fminf(b0, g0), elty = fminf(b1, g1);
        float erbx = fmaxf(b2, g2), erby = fmaxf(b3, g3);
        float ew = fmaxf(erbx - eltx, 0.0f), eh = fmaxf(erby - elty, 0.0f);
        float earea = ew * eh;
        float giou = iou - (earea - uni) / earea;

        // normalized bbox L1 (sequential f32)
        float cb = fabsf(bn0 - gn0);
        cb = cb + fabsf(bn1 - gn1);
        cb = cb + fabsf(bn2 - gn2);
        cb = cb + fabsf(bn3 - gn3);
        // pose L1
        float ct = fabsf(p0 - t0); ct = ct + fabsf(p1 - t1); ct = ct + fabsf(p2 - t2);
        float cr = fabsf(p3 - r0); cr = cr + fabsf(p4 - r1); cr = cr + fabsf(p5 - r2);

        float d = 5.0f * cb;
        d = d + cc2;
        d = d + 2.0f * (-giou);
        d = d + (both ? 0.0f : 100.0f);
        d = d + ct;
        d = d + cr;
        d = d + fgadd;

        CT[(size_t)r * GN] = d;

        // bottom-5 via u64 key cascade (order-isomorphic to (cost,i) lex)
        u64 key = ((u64)fkey(d) << 32) | (unsigned int)i;
        if (key < ck[4]) {
#pragma unroll
            for (int k = 0; k < 5; k++) {
                u64 mn = key < ck[k] ? key : ck[k];
                u64 mx = key < ck[k] ? ck[k] : key;
                ck[k] = mn; key = mx;
            }
        }
        // top-5 iou via max/min network
        if (iou > iv[4]) {
            float fv = iou;
#pragma unroll
            for (int k = 0; k < 5; k++) {
                float mx = fmaxf(fv, iv[k]);
                fv = fminf(fv, iv[k]);
                iv[k] = mx;
            }
        }
    }

    // pack one 64B record and store as 4x16B (full-line write)
    const int col = b * GN + j;
    u64 buf[8];
#pragma unroll
    for (int k = 0; k < 5; k++) buf[k] = ck[k];
    float* bf = (float*)(buf + 5);
#pragma unroll
    for (int k = 0; k < 5; k++) bf[k] = iv[k];
    bf[5] = 0.0f;                                   // pad -> full 64B line
    ulonglong2* dst = (ulonglong2*)(rec + (((size_t)col * NPART) + part) * 8);
    const ulonglong2* src = (const ulonglong2*)buf;
    dst[0] = src[0]; dst[1] = src[1]; dst[2] = src[2]; dst[3] = src[3];
}

// ---------------- per-batch back-end: dk-merge | stalefix | assign | outputs ------------------
// One block per batch, 1024 threads. ALL intermediate state in LDS (nothing global except
// costT/rec reads and out writes). rowJS = min claiming column per row (== __ffsll of the old
// rowmask); stale fix REPLACES rowJS; assignment atomicMins only rowcnt==0 rows (disjoint from
// candidate rows) so phase-E candidate checks are race-free.
__global__ __launch_bounds__(1024) void k_back(const float* __restrict__ costT,
                                               const u64* __restrict__ rec,
                                               int* __restrict__ out) {
#pragma clang fp contract(off)
    const int b = blockIdx.x;
    const int t = threadIdx.x;
    const int lane = t & 63;
    const int wid = t >> 6;                          // 16 waves

    __shared__ int rowJS[QN];                        // 16 KB: min claiming col / stale bj / assigns
    __shared__ int rowcntS[QN];                      // 16 KB: original claim count
    __shared__ int colcntS[GN];                      // 1 KB
    __shared__ u64 candK[GN][5];                     // 10 KB: raw top-5 keys per column
    __shared__ int dkS[GN];                          // 1 KB
    __shared__ u64 staleAminS[GN];                   // 2 KB
    __shared__ u64 aminS[GN];                        // 2 KB
    __shared__ int staleListS[1024];                 // 4 KB (bound: <=640 stale rows)
    __shared__ int staleCntS, fbCountS;
    __shared__ int fbLS[GN];                         // 1 KB
    __shared__ u64 red[1024];                        // 8 KB

    // ---- init ----
#pragma unroll
    for (int s = 0; s < 4; s++) { rowJS[s * 1024 + t] = 0x7FFFFFFF; rowcntS[s * 1024 + t] = 0; }
    if (t < GN) { colcntS[t] = 0; staleAminS[t] = ~0ull; aminS[t] = ~0ull; }
    if (t == 0) { staleCntS = 0; fbCountS = 0; }
    __syncthreads();

    // ---- phase A: per-column merge of 64 part-records (wave butterfly), claims ----
    for (int c = 0; c < 16; c++) {
        const int j = wid * 16 + c;
        const u64* R0 = rec + (((size_t)(b * GN + j) * NPART) + lane) * 8;
        u64 rv[5]; float fr[5];
        const float* F0 = (const float*)(R0 + 5);
#pragma unroll
        for (int k = 0; k < 5; k++) { rv[k] = R0[k]; fr[k] = F0[k]; }
        for (int off = 1; off < 64; off <<= 1) {
            u64 ov[5]; float of[5];
#pragma unroll
            for (int m = 0; m < 5; m++) {
                ov[m] = __shfl_xor(rv[m], off, 64);
                of[m] = __shfl_xor(fr[m], off, 64);
            }
#pragma unroll
            for (int m = 0; m < 5; m++) {
                u64 key = ov[m];
                if (key < rv[4]) {
#pragma unroll
                    for (int k = 0; k < 5; k++) {
                        u64 mn = key < rv[k] ? key : rv[k];
                        u64 mx = key < rv[k] ? rv[k] : key;
                        rv[k] = mn; key = mx;
                    }
                }
                float fv = of[m];
                if (fv > fr[4]) {
#pragma unroll
                    for (int k = 0; k < 5; k++) {
                        float mx = fmaxf(fv, fr[k]);
                        fv = fminf(fv, fr[k]);
                        fr[k] = mx;
                    }
                }
            }
        }
        if (lane == 0) {
            float sum = ((((fr[0] + fr[1]) + fr[2]) + fr[3]) + fr[4]);  // desc, sequential
            int dk = (int)sum;
            if (dk < 1) dk = 1;
            if (dk > 5) dk = 5;
            dkS[j] = dk;
#pragma unroll
            for (int k = 0; k < 5; k++) candK[j][k] = rv[k];
            for (int k = 0; k < dk; k++) {
                int i = (int)(unsigned int)(rv[k] & 0xFFFFFFFFull);
                atomicAdd(&rowcntS[i], 1);
                atomicMin(&rowJS[i], j);
            }
        }
    }
    __syncthreads();

    // ---- phase B1: detect (stale list + colcnt for unique matches) ----
#pragma unroll
    for (int s = 0; s < 4; s++) {
        const int i = s * 1024 + t;
        const int cnt = rowcntS[i];
        if (cnt == 1) {
            atomicAdd(&colcntS[rowJS[i]], 1);
        } else if (cnt > 1) {
            int e = atomicAdd(&staleCntS, 1);
            staleListS[e] = i;
        }
    }
    __syncthreads();

    // ---- phase B2: stale fix, all 16 waves grid-stride the list (load-balanced) ----
    const int nStale = staleCntS;
    for (int e = wid; e < nStale; e += 16) {
        const int iL = staleListS[e];
        const float* cb = costT + ((size_t)(b * QN) + iL) * GN;   // contiguous row
        float best = FLT_MAX; int bj = GN;
        for (int k = 0; k < GN; k += 64) {
            int jj = k + lane;
            float v = cb[jj];
            if (lexLessF(v, jj, best, bj)) { best = v; bj = jj; }
        }
        for (int off = 32; off > 0; off >>= 1) {
            float ov = __shfl_down(best, off, 64);
            int oj = __shfl_down(bj, off, 64);
            if (lexLessF(ov, oj, best, bj)) { best = ov; bj = oj; }
        }
        if (lane == 0) {
            rowJS[iL] = bj;                           // REPLACE (each stale row owned by 1 wave)
            atomicAdd(&colcntS[bj], 1);
            float pv = best + 100000.0f;
            u64 key = ((u64)fkey(pv) << 32) | (unsigned int)iL;
            atomicMin(&staleAminS[bj], key);
        }
    }
    __syncthreads();

    // ---- phase C: candidate assign vs FINAL colcnt (threads 0..255) ----
    if (t < GN) {
        if (colcntS[t] == 0) {
            bool found = false;
            u64 best = ~0ull;
#pragma unroll
            for (int k = 0; k < 5; k++) {
                if (!found) {
                    u64 kk = candK[t][k];
                    int i = (int)(unsigned int)(kk & 0xFFFFFFFFull);
                    if (rowcntS[i] == 0) { best = kk; found = true; }
                }
            }
            if (found) {
                aminS[t] = best;
            } else {
                int e = atomicAdd(&fbCountS, 1);
                fbLS[e] = t;
            }
        }
    }
    __syncthreads();

    // ---- phase D: fallback scans (whole block per entry) ----
    const int nfb = fbCountS;
    for (int e = 0; e < nfb; e++) {
        const int jc = fbLS[e];
        const float* C = costT + ((size_t)(b * QN)) * GN + jc;
        u64 best = ~0ull;
#pragma unroll
        for (int s = 0; s < 4; s++) {
            int r = s * 1024 + t;
            if (rowcntS[r] == 0) {
                float v = C[(size_t)r * GN];
                u64 key = ((u64)fkey(v) << 32) | (unsigned int)r;
                best = key < best ? key : best;
            }
        }
        red[t] = best;
        __syncthreads();
        for (int s2 = 512; s2 > 0; s2 >>= 1) {
            if (t < s2) { u64 o = red[t + s2]; if (o < red[t]) red[t] = o; }
            __syncthreads();
        }
        if (t == 0) aminS[jc] = red[0];
        __syncthreads();
    }

    // ---- phase E: apply assignments + outcols (threads 0..255) ----
    if (t < GN) {
        const int col = b * GN + t;
        int* o = out + (size_t)2 * BN * QN + col;
        if (colcntS[t] == 0) {
            u64 key = aminS[t];
            int r = (int)(unsigned int)(key & 0xFFFFFFFFull);
            atomicMin(&rowJS[r], t);                 // only rowcnt==0 rows: disjoint from cands
            *o = r;
        } else {
            float best = FLT_MAX; int bi = INT_MAX;
            const int dk = dkS[t];
            for (int k = 0; k < 5; k++) {
                if (k < dk) {
                    u64 kk = candK[t][k];
                    int i = (int)(unsigned int)(kk & 0xFFFFFFFFull);
                    if (rowJS[i] == t) {             // claimed-by-me (== old rowmask bit test)
                        float pv = funkey((unsigned int)(kk >> 32)) + 100000.0f;
                        if (lexLessF(pv, i, best, bi)) { best = pv; bi = i; }
                    }
                }
            }
            const u64 sk = staleAminS[t];
            if (sk != ~0ull) {
                float pv = funkey((unsigned int)(sk >> 32));
                int ei = (int)(unsigned int)(sk & 0xFFFFFFFFull);
                if (lexLessF(pv, ei, best, bi)) { best = pv; bi = ei; }
            }
            *o = (bi == INT_MAX) ? 0 : bi;
        }
    }
    __syncthreads();

    // ---- phase F: outrows (final rowJS incl. assignment mins) ----
#pragma unroll
    for (int s = 0; s < 4; s++) {
        const int i = s * 1024 + t;
        const int rj = rowJS[i];
        const int sel = (rj < GN) ? 1 : 0;
        out[(size_t)b * QN + i] = sel;
        out[(size_t)BN * QN + (size_t)b * QN + i] = sel ? rj : 0;
    }
}

extern "C" void kernel_launch(void* const* d_in, const int* in_sizes, int n_in,
                              void* d_out, int out_size, void* d_ws, size_t ws_size,
                              hipStream_t stream) {
    const float* logits = (const float*)d_in[0];
    const float* pboxes = (const float*)d_in[1];
    const float* pposes = (const float*)d_in[2];
    const int* labels = (const int*)d_in[3];
    const float* gtb = (const float*)d_in[4];
    const float* gtt = (const float*)d_in[5];
    const float* gtr = (const float*)d_in[6];
    const float* img = (const float*)d_in[7];
    const float* imgt = (const float*)d_in[8];
    int* out = (int*)d_out;

    char* p = (char*)d_ws;
    float* costT = (float*)p;            p += (size_t)BN * QN * GN * 4;        // 64 MiB
    u64* rec = (u64*)p;                  p += (size_t)BN * GN * NPART * 64;    // 16 MiB (64B/record)

    k_main<<<BN * NPART, 256, 0, stream>>>(logits, labels, gtb, gtt, gtr, imgt,
                                           pboxes, pposes, img, costT, rec);
    k_back<<<BN, 1024, 0, stream>>>(costT, rec, out);
}

// Round 16
// 211.734 us; speedup vs baseline: 1.6730x; 1.6730x over previous
//
#include <hip/hip_runtime.h>
#include <cfloat>
#include <climits>
#include <math.h>

#define BN 16
#define QN 4096
#define GN 256
#define CN 80
#define NPART 64           // row parts in k_main (64 rows each)
#define RPP (QN / NPART)   // 64

typedef unsigned long long u64;

__device__ __forceinline__ bool lexLessF(float a, int ia, float b, int ib) {
    return (a < b) || (a == b && ia < ib);
}
// IEEE order-isomorphic u32 key (no NaNs in this data)
__device__ __forceinline__ unsigned int fkey(float f) {
    unsigned int b = __float_as_uint(f);
    return b ^ ((b >> 31) ? 0xFFFFFFFFu : 0x80000000u);
}
__device__ __forceinline__ float funkey(unsigned int k) {
    unsigned int b = k ^ ((k >> 31) ? 0x80000000u : 0xFFFFFFFFu);
    return __uint_as_float(b);
}

// ---------------- fully-fused front-end: zero | prm | class | fg | cost | selection ----------
// Each block owns rows i0..i0+63 of batch b exclusively. All numerics identical expressions
// (contract off) -> bit-identical costs. fg phase emits a both-bitmask so the main loop does
// NOT recompute the 8 bounds compares per cell. Lc stores 2*cc (exact f32 doubling).
__global__ __launch_bounds__(256) void k_main(
    const float* __restrict__ logits, const int* __restrict__ labels,
    const float* __restrict__ gtb, const float* __restrict__ gtt,
    const float* __restrict__ gtr, const float* __restrict__ imgt,
    const float* __restrict__ pboxes, const float* __restrict__ pposes,
    const float* __restrict__ img,
    float* __restrict__ costT, u64* __restrict__ rec,
    u64* __restrict__ zbase, int zn) {
#pragma clang fp contract(off)
    const int j = threadIdx.x;
    const int b = blockIdx.x >> 6;
    const int part = blockIdx.x & 63;
    const int i0 = part * RPP;

    __shared__ float Lc[RPP * CN];       // 64x80 2x focal class costs (20.5 KB)
    __shared__ float Lb[8 * GN];         // X0,Y0,X1,Y1,LOX,HIX,LOY,HIY per column (8 KB)
    __shared__ u64 Lboth[RPP][4];        // both-bitmask per row (2 KB)
    __shared__ unsigned int Lany[RPP * 4];
    __shared__ float4 Rsh[RPP][5];

    // ---- 0. zero-slice of the zero region (consumed by k_dk/k_fix5/k_fba) ----
    for (int z = blockIdx.x * 256 + j; z < zn; z += 1024 * 256) zbase[z] = 0ull;

    // ---- 1. per-column params (identical expressions) ----
    const float* g = gtb + ((size_t)(b * GN + j)) * 4;
    const float g0 = g[0], g1 = g[1], g2 = g[2], g3 = g[3];
    const float* it = imgt + ((size_t)(b * GN + j)) * 4;
    const float gn0 = g0 / it[0], gn1 = g1 / it[1], gn2 = g2 / it[2], gn3 = g3 / it[3];
    const float t0 = gtt[(b * GN + j) * 3 + 0], t1 = gtt[(b * GN + j) * 3 + 1],
                t2 = gtt[(b * GN + j) * 3 + 2];
    const float r0 = gtr[(b * GN + j) * 3 + 0], r1 = gtr[(b * GN + j) * 3 + 1],
                r2 = gtr[(b * GN + j) * 3 + 2];
    const float ga = (g2 - g0) * (g3 - g1);
    {
        float gcx = (g0 + g2) * 0.5f, gcy = (g1 + g3) * 0.5f;
        float gw = g2 - g0, gh = g3 - g1;
        float X0 = gcx - gw * 0.5f, Y0 = gcy - gh * 0.5f;
        float X1 = gcx + gw * 0.5f, Y1 = gcy + gh * 0.5f;
        float Wd = X1 - X0, Hd = Y1 - Y0;
        Lb[0 * GN + j] = X0;  Lb[1 * GN + j] = Y0;
        Lb[2 * GN + j] = X1;  Lb[3 * GN + j] = Y1;
        Lb[4 * GN + j] = gcx - 2.5f * Wd; Lb[5 * GN + j] = gcx + 2.5f * Wd;
        Lb[6 * GN + j] = gcy - 2.5f * Hd; Lb[7 * GN + j] = gcy + 2.5f * Hd;
    }
    const int lab = labels[b * GN + j];

    // ---- 2. class focal for the block's 64 rows x 80 classes (contiguous 20 KB span) ----
    const float* lbase = logits + ((size_t)(b * QN + i0)) * CN;
#pragma unroll
    for (int q = 0; q < 20; q++) {
        int idx = q * 256 + j;
        float x = lbase[idx];
        float e = (float)exp(-(double)x);
        float pr = 1.0f / (1.0f + e);
        float om = 1.0f - pr;
        float lneg = (float)log((double)(om + 1e-8f));
        float lpos = (float)log((double)(pr + 1e-8f));
        float neg = (0.75f * (pr * pr)) * (-lneg);
        float pos = (0.25f * (om * om)) * (-lpos);
        Lc[idx] = 2.0f * (pos - neg);    // pre-doubled: 2*cc is exact in f32
    }

    // ---- 3. row staging ----
    if (threadIdx.x < RPP) {
        const int i = i0 + threadIdx.x;
        const float im0 = img[b * 4 + 0], im1 = img[b * 4 + 1];
        const float im2 = img[b * 4 + 2], im3 = img[b * 4 + 3];
        const float4 bx = *reinterpret_cast<const float4*>(pboxes + ((size_t)(b * QN + i)) * 4);
        const float b0 = bx.x, b1 = bx.y, b2 = bx.z, b3 = bx.w;
        const float2* pp2 = reinterpret_cast<const float2*>(pposes + ((size_t)(b * QN + i)) * 6);
        const float2 q0 = pp2[0], q1 = pp2[1], q2 = pp2[2];
        const float bn0 = b0 / im0, bn1 = b1 / im1, bn2 = b2 / im2, bn3 = b3 / im3;
        const float a1 = (b2 - b0) * (b3 - b1);
        const float ax = (b0 + b2) * 0.5f, ay = (b1 + b3) * 0.5f;
        Rsh[threadIdx.x][0] = make_float4(b0, b1, b2, b3);
        Rsh[threadIdx.x][1] = make_float4(bn0, bn1, bn2, bn3);
        Rsh[threadIdx.x][2] = make_float4(ax, ay, a1, 0.0f);
        Rsh[threadIdx.x][3] = make_float4(q0.x, q0.y, q1.x, q1.y);
        Rsh[threadIdx.x][4] = make_float4(q2.x, q2.y, 0.0f, 0.0f);
    }
    __syncthreads();

    // ---- 4. fg + both-bits: thread t -> row t&63, gt chunk t>>6 (64 gts) ----
    {
        const int r = threadIdx.x & 63, ch = threadIdx.x >> 6;
        const float axr = Rsh[r][2].x, ayr = Rsh[r][2].y;
        bool any = false;
        u64 bothbits = 0;
        const int jb = ch * 64;
#pragma unroll 8
        for (int m = 0; m < 64; m++) {
            int jj = jb + m;
            bool ib = (axr > Lb[0 * GN + jj]) && (axr < Lb[2 * GN + jj]) &&
                      (ayr > Lb[1 * GN + jj]) && (ayr < Lb[3 * GN + jj]);
            bool ic = (axr > Lb[4 * GN + jj]) && (axr < Lb[5 * GN + jj]) &&
                      (ayr > Lb[6 * GN + jj]) && (ayr < Lb[7 * GN + jj]);
            any |= (ib || ic);
            if (ib && ic) bothbits |= (1ull << m);
        }
        Lany[r * 4 + ch] = any ? 1u : 0u;
        Lboth[r][ch] = bothbits;
    }
    __syncthreads();
    if (threadIdx.x < RPP) {
        unsigned int a = 0;
#pragma unroll
        for (int c = 0; c < 4; c++) a |= Lany[threadIdx.x * 4 + c];
        Rsh[threadIdx.x][2].w = a ? 0.0f : 10000.0f;   // fgadd folded into row record
    }
    __syncthreads();

    // ---- 5. cost + selection main loop ----
    float* CT = costT + ((size_t)(b * QN) + i0) * GN + j;
    const int jw = j >> 6, jb63 = j & 63;

    u64 ck[5]; float iv[5];
#pragma unroll
    for (int k = 0; k < 5; k++) { ck[k] = ~0ull; iv[k] = -1.0f; }

    for (int r = 0; r < RPP; r++) {
        const int i = i0 + r;
        const float4 R0 = Rsh[r][0];
        const float4 R1 = Rsh[r][1];
        const float4 R2 = Rsh[r][2];
        const float4 R3 = Rsh[r][3];
        const float4 R4 = Rsh[r][4];
        const float b0 = R0.x, b1 = R0.y, b2 = R0.z, b3 = R0.w;
        const float bn0 = R1.x, bn1 = R1.y, bn2 = R1.z, bn3 = R1.w;
        const float a1 = R2.z, fgadd = R2.w;
        const float p0 = R3.x, p1 = R3.y, p2 = R3.z, p3 = R3.w;
        const float p4 = R4.x, p5 = R4.y;
        const float cc2 = Lc[r * CN + lab];
        const bool both = (Lboth[r][jw] >> jb63) & 1;

        // iou / giou (f32, reference op order)
        float ltx = fmaxf(b0, g0), lty = fmaxf(b1, g1);
        float rbx = fminf(b2, g2), rby = fminf(b3, g3);
        float w = fmaxf(rbx - ltx, 0.0f), h = fmaxf(rby - lty, 0.0f);
        float inter = w * h;
        float uni = (a1 + ga) - inter;
        float iou = inter / uni;
        float eltx = fminf(b0, g0), elty = fminf(b1, g1);
        float erbx = fmaxf(b2, g2), erby = fmaxf(b3, g3);
        float ew = fmaxf(erbx - eltx, 0.0f), eh = fmaxf(erby - elty, 0.0f);
        float earea = ew * eh;
        float giou = iou - (earea - uni) / earea;

        // normalized bbox L1 (sequential f32)
        float cb = fabsf(bn0 - gn0);
        cb = cb + fabsf(bn1 - gn1);
        cb = cb + fabsf(bn2 - gn2);
        cb = cb + fabsf(bn3 - gn3);
        // pose L1
        float ct = fabsf(p0 - t0); ct = ct + fabsf(p1 - t1); ct = ct + fabsf(p2 - t2);
        float cr = fabsf(p3 - r0); cr = cr + fabsf(p4 - r1); cr = cr + fabsf(p5 - r2);

        float d = 5.0f * cb;
        d = d + cc2;
        d = d + 2.0f * (-giou);
        d = d + (both ? 0.0f : 100.0f);
        d = d + ct;
        d = d + cr;
        d = d + fgadd;

        CT[(size_t)r * GN] = d;

        // bottom-5 via u64 key cascade (order-isomorphic to (cost,i) lex)
        u64 key = ((u64)fkey(d) << 32) | (unsigned int)i;
        if (key < ck[4]) {
#pragma unroll
            for (int k = 0; k < 5; k++) {
                u64 mn = key < ck[k] ? key : ck[k];
                u64 mx = key < ck[k] ? ck[k] : key;
                ck[k] = mn; key = mx;
            }
        }
        // top-5 iou via max/min network
        if (iou > iv[4]) {
            float fv = iou;
#pragma unroll
            for (int k = 0; k < 5; k++) {
                float mx = fmaxf(fv, iv[k]);
                fv = fminf(fv, iv[k]);
                iv[k] = mx;
            }
        }
    }

    // pack one 64B record and store as 4x16B (full-line write)
    const int col = b * GN + j;
    u64 buf[8];
#pragma unroll
    for (int k = 0; k < 5; k++) buf[k] = ck[k];
    float* bf = (float*)(buf + 5);
#pragma unroll
    for (int k = 0; k < 5; k++) bf[k] = iv[k];
    bf[5] = 0.0f;                                   // pad -> full 64B line
    ulonglong2* dst = (ulonglong2*)(rec + (((size_t)col * NPART) + part) * 8);
    const ulonglong2* src = (const ulonglong2*)buf;
    dst[0] = src[0]; dst[1] = src[1]; dst[2] = src[2]; dst[3] = src[3];
}

// ---------------- merge parts (wave butterfly), dk, rowmask, rowcnt, amin/staleAmin init ----
// NPART=64: exactly one record per lane; no pre-merge needed.
__global__ __launch_bounds__(256) void k_dk(const u64* __restrict__ rec,
                                            float* __restrict__ candcv, int* __restrict__ candci,
                                            int* __restrict__ dkArr, u64* __restrict__ rowmask,
                                            u64* __restrict__ amin, int* __restrict__ rowcnt,
                                            u64* __restrict__ staleAmin) {
#pragma clang fp contract(off)
    const int lane = threadIdx.x & 63;
    const int colIdx = blockIdx.x * 4 + (threadIdx.x >> 6);   // 4 waves/block
    const int b = colIdx >> 8, j = colIdx & 255;
    const u64* R0 = rec + (((size_t)colIdx * NPART) + lane) * 8;
    u64 rv[5]; float fr[5];
    const float* F0 = (const float*)(R0 + 5);
#pragma unroll
    for (int k = 0; k < 5; k++) { rv[k] = R0[k]; fr[k] = F0[k]; }
    for (int off = 1; off < 64; off <<= 1) {
        u64 ov[5]; float of[5];
#pragma unroll
        for (int m = 0; m < 5; m++) {
            ov[m] = __shfl_xor(rv[m], off, 64);
            of[m] = __shfl_xor(fr[m], off, 64);
        }
#pragma unroll
        for (int m = 0; m < 5; m++) {
            u64 key = ov[m];
            if (key < rv[4]) {
#pragma unroll
                for (int k = 0; k < 5; k++) {
                    u64 mn = key < rv[k] ? key : rv[k];
                    u64 mx = key < rv[k] ? rv[k] : key;
                    rv[k] = mn; key = mx;
                }
            }
            float fv = of[m];
            if (fv > fr[4]) {
#pragma unroll
                for (int k = 0; k < 5; k++) {
                    float mx = fmaxf(fv, fr[k]);
                    fv = fminf(fv, fr[k]);
                    fr[k] = mx;
                }
            }
        }
    }

    if (lane == 0) {
        float sum = ((((fr[0] + fr[1]) + fr[2]) + fr[3]) + fr[4]);  // desc order, sequential
        int dk = (int)sum;
        if (dk < 1) dk = 1;
        if (dk > 5) dk = 5;
        dkArr[colIdx] = dk;
        amin[colIdx] = ~0ull;
        staleAmin[colIdx] = ~0ull;
#pragma unroll
        for (int k = 0; k < 5; k++) {
            candcv[(size_t)colIdx * 5 + k] = funkey((unsigned int)(rv[k] >> 32));
            candci[(size_t)colIdx * 5 + k] = (int)(unsigned int)(rv[k] & 0xFFFFFFFFull);
        }
        for (int k = 0; k < dk; k++) {
            int i = (int)(unsigned int)(rv[k] & 0xFFFFFFFFull);
            atomicOr(&rowmask[((size_t)(b * QN + i)) * 4 + (j >> 6)], 1ull << (j & 63));
            atomicAdd(&rowcnt[b * QN + i], 1);
        }
    }
}

// ---------------- fused: detect+wave-fix+colcnt (blocks 0..255) | candidate-assign (256..271) ----
__global__ __launch_bounds__(256) void k_fix5(const float* __restrict__ costT,
                                              u64* __restrict__ rowmask,
                                              int* __restrict__ colcnt,
                                              const int* __restrict__ rowcnt,
                                              const float* __restrict__ candcv,
                                              const int* __restrict__ candci,
                                              u64* __restrict__ amin,
                                              u64* __restrict__ staleAmin,
                                              int* __restrict__ fbCount,
                                              int* __restrict__ fbL) {
    if (blockIdx.x < 256) {
        // ---- row side: per-thread detect, wave-cooperative fix ----
        const int b = blockIdx.x >> 4;
        const int i = (blockIdx.x & 15) * 256 + threadIdx.x;
        const int lane = threadIdx.x & 63;
        const int cnt = rowcnt[b * QN + i];
        if (cnt == 1) {
            const u64* rm = rowmask + ((size_t)(b * QN + i)) * 4;
            u64 w0 = rm[0], w1 = rm[1], w2 = rm[2], w3 = rm[3];
            u64 w; int base;
            if (w0) { w = w0; base = 0; }
            else if (w1) { w = w1; base = 64; }
            else if (w2) { w = w2; base = 128; }
            else { w = w3; base = 192; }
            int jj = base + (__ffsll((long long)w) - 1);
            atomicAdd(&colcnt[b * GN + jj], 1);
        }
        // wave-cooperative fix of flagged (stale) rows, one at a time
        u64 bal = __ballot(cnt > 1);
        while (bal) {
            const int L = __ffsll((long long)bal) - 1;
            bal &= bal - 1;
            const int iL = (i & ~63) | L;
            const float* cb = costT + ((size_t)(b * QN) + iL) * GN;   // contiguous row
            float best = FLT_MAX; int bj = GN;
            for (int k = 0; k < GN; k += 64) {
                int jj = k + lane;
                float v = cb[jj];
                if (lexLessF(v, jj, best, bj)) { best = v; bj = jj; }
            }
            for (int off = 32; off > 0; off >>= 1) {
                float ov = __shfl_down(best, off, 64);
                int oj = __shfl_down(bj, off, 64);
                if (lexLessF(ov, oj, best, bj)) { best = ov; bj = oj; }
            }
            if (lane == 0) {
                u64* rm = rowmask + ((size_t)(b * QN + iL)) * 4;
                rm[0] = ((bj >> 6) == 0) ? (1ull << (bj & 63)) : 0ull;
                rm[1] = ((bj >> 6) == 1) ? (1ull << (bj & 63)) : 0ull;
                rm[2] = ((bj >> 6) == 2) ? (1ull << (bj & 63)) : 0ull;
                rm[3] = ((bj >> 6) == 3) ? (1ull << (bj & 63)) : 0ull;
                atomicAdd(&colcnt[b * GN + bj], 1);
                // record stale winner for outcols: pv = best + 100000, tie-break by row index
                float pv = best + 100000.0f;
                u64 key = ((u64)fkey(pv) << 32) | (unsigned int)iL;
                atomicMin(&staleAmin[b * GN + bj], key);
            }
        }
        return;
    }

    // ---- candidate-based assign: 16 blocks, 1 thread/column ----
    const int b = blockIdx.x - 256;
    const int j = threadIdx.x;
    const int col = b * GN + j;

    if (colcnt[col] == 0) {   // racy read; monotone => spurious work discarded later
        bool found = false;
        u64 best = ~0ull;
#pragma unroll
        for (int k = 0; k < 5; k++) {
            if (!found) {
                int i = candci[(size_t)col * 5 + k];
                if (rowcnt[b * QN + i] == 0) {
                    best = ((u64)fkey(candcv[(size_t)col * 5 + k]) << 32) | (unsigned int)i;
                    found = true;
                }
            }
        }
        if (found) {
            amin[col] = best;
        } else {
            int e = atomicAdd(fbCount, 1);   // rare: resolve in k_fba with full parallelism
            fbL[e] = col;
        }
    }
}

// ---------------- fused: finalize+outcols (blocks 0..15) | fallback scans (blocks 16..271) ----
// Blocks 0..15 per column: colcnt==0 -> assignment (amin row; OR rowmask; write outcols);
// colcnt!=0 -> candidate/stale outcols (rowmask bits for matched cols are final after k_fix5;
// assignment ORs never touch matched columns' bits). Fallback cols handled by scan blocks.
__global__ __launch_bounds__(256) void k_fba(const float* __restrict__ costT,
                                             const int* __restrict__ rowcnt,
                                             const int* __restrict__ colcnt,
                                             const u64* __restrict__ amin,
                                             const int* __restrict__ fbCount,
                                             const int* __restrict__ fbL,
                                             const float* __restrict__ candcv,
                                             const int* __restrict__ candci,
                                             const int* __restrict__ dkArr,
                                             const u64* __restrict__ staleAmin,
                                             u64* __restrict__ rowmask,
                                             int* __restrict__ out) {
    if (blockIdx.x < BN) {
        const int b = blockIdx.x;
        const int j = threadIdx.x;
        const int col = b * GN + j;
        int* o = out + (size_t)2 * BN * QN + col;
        if (colcnt[col] == 0) {
            u64 key = amin[col];
            if (key == ~0ull) return;        // true fallback: scan blocks own it
            int r = (int)(unsigned int)(key & 0xFFFFFFFFull);
            atomicOr(&rowmask[((size_t)(b * QN + r)) * 4 + (j >> 6)], 1ull << (j & 63));
            *o = r;
            return;
        }
        // matched column: candidate/stale outcols
        const u64 bit = 1ull << (j & 63);
        const int w = j >> 6;
        float best = FLT_MAX; int bi = INT_MAX;
        const int dk = dkArr[col];
        for (int k = 0; k < 5; k++) {
            if (k < dk) {
                int i = candci[(size_t)col * 5 + k];
                if (rowmask[((size_t)(b * QN + i)) * 4 + w] & bit) {
                    float pv = candcv[(size_t)col * 5 + k] + 100000.0f;
                    if (lexLessF(pv, i, best, bi)) { best = pv; bi = i; }
                }
            }
        }
        const u64 sk = staleAmin[col];
        if (sk != ~0ull) {
            float pv = funkey((unsigned int)(sk >> 32));
            int ei = (int)(unsigned int)(sk & 0xFFFFFFFFull);
            if (lexLessF(pv, ei, best, bi)) { best = pv; bi = ei; }
        }
        *o = (bi == INT_MAX) ? 0 : bi;
        return;
    }
    // ---- fallback scans: one block per fbL entry (grid-stride) ----
    __shared__ u64 red[256];
    const int n = *fbCount;
    const int t = threadIdx.x;
    for (int e = blockIdx.x - BN; e < n; e += 256) {
        const int col = fbL[e];
        const int b = col >> 8, j = col & 255;
        if (colcnt[col] != 0) continue;      // spuriously recorded (outcols written by 0..15)
        const float* C = costT + ((size_t)(b * QN)) * GN + j;
        const int* rc = rowcnt + b * QN;
        u64 best = ~0ull;
#pragma unroll
        for (int s = 0; s < 16; s++) {
            int r = s * 256 + t;
            if (rc[r] == 0) {
                float v = C[(size_t)r * GN];
                u64 key = ((u64)fkey(v) << 32) | (unsigned int)r;
                best = key < best ? key : best;
            }
        }
        red[t] = best;
        __syncthreads();
        for (int s2 = 128; s2 > 0; s2 >>= 1) {
            if (t < s2) { u64 o = red[t + s2]; if (o < red[t]) red[t] = o; }
            __syncthreads();
        }
        if (t == 0) {
            int r = (int)(unsigned int)(red[0] & 0xFFFFFFFFull);
            atomicOr(&rowmask[((size_t)(b * QN + r)) * 4 + (j >> 6)], 1ull << (j & 63));
            out[(size_t)2 * BN * QN + col] = r;
        }
        __syncthreads();   // red reused next iteration
    }
}

// ---------------- outrows only (reads final rowmask) ----------------
__global__ __launch_bounds__(256) void k_out(const u64* __restrict__ rowmask,
                                             int* __restrict__ out) {
    const int b = blockIdx.x >> 4;
    const int i = (blockIdx.x & 15) * 256 + threadIdx.x;
    const u64* rm = rowmask + ((size_t)(b * QN + i)) * 4;
    u64 w0 = rm[0], w1 = rm[1], w2 = rm[2], w3 = rm[3];
    int sel = (w0 | w1 | w2 | w3) ? 1 : 0;
    int g = 0;
    if (w0) g = __ffsll((long long)w0) - 1;
    else if (w1) g = 64 + __ffsll((long long)w1) - 1;
    else if (w2) g = 128 + __ffsll((long long)w2) - 1;
    else if (w3) g = 192 + __ffsll((long long)w3) - 1;
    out[(size_t)b * QN + i] = sel;
    out[(size_t)BN * QN + (size_t)b * QN + i] = g;
}

extern "C" void kernel_launch(void* const* d_in, const int* in_sizes, int n_in,
                              void* d_out, int out_size, void* d_ws, size_t ws_size,
                              hipStream_t stream) {
    const float* logits = (const float*)d_in[0];
    const float* pboxes = (const float*)d_in[1];
    const float* pposes = (const float*)d_in[2];
    const int* labels = (const int*)d_in[3];
    const float* gtb = (const float*)d_in[4];
    const float* gtt = (const float*)d_in[5];
    const float* gtr = (const float*)d_in[6];
    const float* img = (const float*)d_in[7];
    const float* imgt = (const float*)d_in[8];
    int* out = (int*)d_out;

    char* p = (char*)d_ws;
    float* costT = (float*)p;            p += (size_t)BN * QN * GN * 4;        // 64 MiB
    u64* rec = (u64*)p;                  p += (size_t)BN * GN * NPART * 64;    // 16 MiB (64B/record)
    // ---- zero region: rowmask | colcnt | fbCount | rowcnt (contiguous) ----
    u64* rowmask = (u64*)p;              size_t rb = (size_t)BN * QN * 4 * 8; p += rb;  // 2 MiB
    int* colcnt = (int*)p;               p += (size_t)BN * GN * 4;             // 16 KiB
    int* fbCount = (int*)p;              p += 64;
    int* rowcnt = (int*)p;               p += (size_t)BN * QN * 4;             // 256 KiB
    // ---- end zero region ----
    float* candcv = (float*)p;           p += (size_t)BN * GN * 5 * 4;         // 80 KiB
    int* candci = (int*)p;               p += (size_t)BN * GN * 5 * 4;         // 80 KiB
    int* dkArr = (int*)p;                p += (size_t)BN * GN * 4;             // 16 KiB
    u64* amin = (u64*)p;                 p += (size_t)BN * GN * 8;             // 32 KiB
    u64* staleAmin = (u64*)p;            p += (size_t)BN * GN * 8;             // 32 KiB (init in k_dk)
    int* fbL = (int*)p;                  p += (size_t)BN * GN * 4;             // 16 KiB

    // zero region size in u64: rowmask(2MiB) + colcnt(16KiB) + 64B + rowcnt(256KiB)
    int zn = (int)((rb + (size_t)BN * GN * 4 + 64 + (size_t)BN * QN * 4) / 8);  // = 296968

    k_main<<<BN * NPART, 256, 0, stream>>>(logits, labels, gtb, gtt, gtr, imgt,
                                           pboxes, pposes, img, costT, rec,
                                           (u64*)rowmask, zn);
    k_dk<<<BN * GN / 4, 256, 0, stream>>>(rec, candcv, candci, dkArr, rowmask, amin, rowcnt,
                                          staleAmin);
    k_fix5<<<256 + BN, 256, 0, stream>>>(costT, rowmask, colcnt, rowcnt, candcv, candci,
                                         amin, staleAmin, fbCount, fbL);
    k_fba<<<BN + 256, 256, 0, stream>>>(costT, rowcnt, colcnt, amin, fbCount, fbL,
                                        candcv, candci, dkArr, staleAmin, rowmask, out);
    k_out<<<256, 256, 0, stream>>>(rowmask, out);
}